// Round 1
// baseline (773.042 us; speedup 1.0000x reference)
//
#include <hip/hip_runtime.h>
#include <hip/hip_bf16.h>
#include <climits>

#define SEG_B 64
#define SEG_L 50000
#define SEG_D 32
#define TOPK  1024
#define EQ_CAP 2048

// Map float to uint32 such that larger float -> larger key (total order, no NaN in inputs).
__device__ __forceinline__ unsigned ordkey(float f) {
    unsigned u = __float_as_uint(f);
    return (u & 0x80000000u) ? ~u : (u | 0x80000000u);
}

// Pass 1: att[p] = dot(x[p,:32], w) + bias.  8 lanes per point, float4 loads (1 KiB/wave/instr).
__global__ void k_att(const float* __restrict__ x, const float* __restrict__ w,
                      const float* __restrict__ bias, float* __restrict__ att) {
    const int lane = threadIdx.x & 63;
    const int q    = lane & 7;      // which float4 of the 32-dim row
    const int sub  = lane >> 3;     // which of the 8 points this wave handles per iter
    const int waveInBlock  = threadIdx.x >> 6;
    const int wavesPerBlock = blockDim.x >> 6;
    const long long waveId     = (long long)blockIdx.x * wavesPerBlock + waveInBlock;
    const long long totalWaves = (long long)gridDim.x * wavesPerBlock;
    const float4 wq = ((const float4*)w)[q];
    const float bb  = bias[0];
    const float4* x4 = (const float4*)x;
    const long long N = (long long)SEG_B * SEG_L;
    for (long long p = waveId * 8 + sub; p < N; p += totalWaves * 8) {
        float4 v = x4[p * 8 + q];
        float dot = v.x * wq.x + v.y * wq.y + v.z * wq.z + v.w * wq.w;
        dot += __shfl_xor(dot, 1);
        dot += __shfl_xor(dot, 2);
        dot += __shfl_xor(dot, 4);
        if (q == 0) att[p] = dot + bb;
    }
}

// Pass 2: per-segment radix select (descending) of the TOPK-th largest att value.
// One block per segment; 3 rounds (11/11/10 bits), 2048-bin LDS histogram.
__global__ void k_select(const float* __restrict__ att,
                         unsigned* __restrict__ tkey, unsigned* __restrict__ need_eq) {
    const int b  = blockIdx.x;
    const int tid = threadIdx.x;
    const int bs  = blockDim.x;
    __shared__ unsigned hist[2048];
    __shared__ unsigned s_prefix, s_k;

    const unsigned shifts[3]   = {21u, 10u, 0u};
    const unsigned widths[3]   = {11u, 11u, 10u};
    const unsigned maskdone[3] = {0x00000000u, 0xFFE00000u, 0xFFFFFC00u};

    if (tid == 0) { s_prefix = 0u; s_k = TOPK; }

    const float* a = att + (long long)b * SEG_L;

    for (int r = 0; r < 3; ++r) {
        const unsigned shift = shifts[r];
        const unsigned nbins = 1u << widths[r];
        const unsigned dmask = nbins - 1u;
        const unsigned mdone = maskdone[r];
        for (int i = tid; i < 2048; i += bs) hist[i] = 0u;
        __syncthreads();                      // hist zeroed + previous round's s_prefix visible
        const unsigned prefix = s_prefix;
        for (int i = tid; i < SEG_L; i += bs) {
            unsigned key = ordkey(a[i]);
            if ((key & mdone) == prefix) {
                atomicAdd(&hist[(key >> shift) & dmask], 1u);
            }
        }
        __syncthreads();
        if (tid == 0) {
            unsigned k = s_k, acc = 0u; unsigned digit = 0u;
            for (int bin = (int)nbins - 1; bin >= 0; --bin) {
                unsigned c = hist[bin];
                if (acc + c >= k) { digit = (unsigned)bin; s_k = k - acc; break; }
                acc += c;
            }
            s_prefix = prefix | (digit << shift);
        }
        __syncthreads();                      // protect hist (thread0 scan) from next round's zeroing
    }
    if (tid == 0) { tkey[b] = s_prefix; need_eq[b] = s_k; }
}

// Pass 3: masked accumulation. Strictly-greater rows accumulate into LDS -> global atomics.
// Equal-to-threshold rows record their index for tie-breaking.
__global__ void k_accum(const float* __restrict__ x, const float* __restrict__ att,
                        const unsigned* __restrict__ tkey,
                        float* __restrict__ g_acc, unsigned* __restrict__ eq_cnt,
                        int* __restrict__ eq_idx) {
    const int b = blockIdx.x;
    const int chunk = blockIdx.y;
    __shared__ float acc[SEG_D];
    if (threadIdx.x < SEG_D) acc[threadIdx.x] = 0.0f;
    __syncthreads();
    const unsigned tk = tkey[b];
    const int per = (SEG_L + gridDim.y - 1) / gridDim.y;
    const int start = chunk * per;
    const int end = min(start + per, SEG_L);
    for (int i = start + (int)threadIdx.x; i < end; i += (int)blockDim.x) {
        const float av = att[(long long)b * SEG_L + i];
        const unsigned key = ordkey(av);
        if (key > tk) {
            const float4* row = (const float4*)(x + ((size_t)b * SEG_L + i) * SEG_D);
            #pragma unroll
            for (int q = 0; q < 8; ++q) {
                float4 v = row[q];
                atomicAdd(&acc[q * 4 + 0], v.x);
                atomicAdd(&acc[q * 4 + 1], v.y);
                atomicAdd(&acc[q * 4 + 2], v.z);
                atomicAdd(&acc[q * 4 + 3], v.w);
            }
        } else if (key == tk) {
            unsigned pos = atomicAdd(&eq_cnt[b], 1u);
            if (pos < EQ_CAP) eq_idx[b * EQ_CAP + pos] = i;
        }
    }
    __syncthreads();
    if (threadIdx.x < SEG_D) atomicAdd(&g_acc[b * SEG_D + threadIdx.x], acc[threadIdx.x]);
}

// Pass 4: tie-break (take m smallest-index equals), mean over L, L2 normalize, write out.
__global__ void k_final(const float* __restrict__ x, const float* __restrict__ g_acc,
                        const unsigned* __restrict__ need_eq, const unsigned* __restrict__ eq_cnt,
                        const int* __restrict__ eq_idx, float* __restrict__ out) {
    const int b = blockIdx.x;
    __shared__ int chosen[TOPK];
    __shared__ float s_res[SEG_D];
    __shared__ float s_norm;
    const int m = (int)need_eq[b];
    const int cnt = min((int)eq_cnt[b], EQ_CAP);
    if (threadIdx.x == 0) {
        int last = -1;
        for (int j = 0; j < m; ++j) {
            int best = INT_MAX;
            for (int t = 0; t < cnt; ++t) {
                int v = eq_idx[b * EQ_CAP + t];
                if (v > last && v < best) best = v;
            }
            chosen[j] = best;
            last = (best == INT_MAX) ? last : best;
        }
    }
    __syncthreads();
    const int d = (int)threadIdx.x;
    if (d < SEG_D) {
        float s = g_acc[b * SEG_D + d];
        for (int j = 0; j < m; ++j) {
            int row = chosen[j];
            if (row != INT_MAX) s += x[((size_t)b * SEG_L + row) * SEG_D + d];
        }
        s_res[d] = s / (float)SEG_L;
    }
    __syncthreads();
    if (threadIdx.x == 0) {
        float n = 0.0f;
        for (int i = 0; i < SEG_D; ++i) n += s_res[i] * s_res[i];
        s_norm = sqrtf(n);
    }
    __syncthreads();
    if (d < SEG_D) {
        out[b * SEG_D + d] = s_res[d] / fmaxf(s_norm, 1e-12f);
    }
}

extern "C" void kernel_launch(void* const* d_in, const int* in_sizes, int n_in,
                              void* d_out, int out_size, void* d_ws, size_t ws_size,
                              hipStream_t stream) {
    const float* x    = (const float*)d_in[0];   // [B*L, 32] fp32
    // d_in[1] = length (int32[64]) — constant L, unused
    const float* w    = (const float*)d_in[2];   // [32]
    const float* bias = (const float*)d_in[3];   // [1]
    float* out = (float*)d_out;                  // [64, 32]

    // Workspace layout (all 4-byte aligned):
    char* p = (char*)d_ws;
    float*    att     = (float*)p;                 p += (size_t)SEG_B * SEG_L * sizeof(float); // 12.8 MB
    float*    g_acc   = (float*)p;                 p += (size_t)SEG_B * SEG_D * sizeof(float); // 8 KB
    unsigned* eq_cnt  = (unsigned*)p;              p += (size_t)SEG_B * sizeof(unsigned);
    unsigned* tkey    = (unsigned*)p;              p += (size_t)SEG_B * sizeof(unsigned);
    unsigned* need_eq = (unsigned*)p;              p += (size_t)SEG_B * sizeof(unsigned);
    int*      eq_idx  = (int*)p;                   p += (size_t)SEG_B * EQ_CAP * sizeof(int);  // 512 KB

    // Zero the atomically-accumulated regions (g_acc + eq_cnt are contiguous).
    hipMemsetAsync(g_acc, 0, (size_t)SEG_B * SEG_D * sizeof(float) + (size_t)SEG_B * sizeof(unsigned), stream);

    // Pass 1: attention scores (reads 409.6 MB of x — the HBM floor).
    k_att<<<2048, 256, 0, stream>>>(x, w, bias, att);

    // Pass 2: per-segment radix select of the 1024th-largest value.
    k_select<<<SEG_B, 1024, 0, stream>>>(att, tkey, need_eq);

    // Pass 3: masked sum (strict >) + equal-index collection.
    dim3 g3(SEG_B, 16);
    k_accum<<<g3, 256, 0, stream>>>(x, att, tkey, g_acc, eq_cnt, eq_idx);

    // Pass 4: tie-break, mean, L2 normalize.
    k_final<<<SEG_B, 64, 0, stream>>>(x, g_acc, need_eq, eq_cnt, eq_idx, out);
}